// Round 2
// baseline (198.798 us; speedup 1.0000x reference)
//
#include <hip/hip_runtime.h>
#include <hip/hip_bf16.h>
#include <stdint.h>

#define M_DIM 8192
#define N_DIM 8192
#define D_DIM 512
#define BM 128
#define BN 128
#define BK 64
#define KITERS (D_DIM / BK)   // 8

typedef __bf16 bf16x8 __attribute__((ext_vector_type(8)));
typedef float f32x4 __attribute__((ext_vector_type(4)));

__device__ inline void gload_lds16(const void* g, void* l) {
  __builtin_amdgcn_global_load_lds(
      (const __attribute__((address_space(1))) void*)g,
      (__attribute__((address_space(3))) void*)l, 16, 0, 0);
}

// 256 threads = 4 waves; one wave per row; fully coalesced.
__global__ __launch_bounds__(256) void prep_kernel(
    const float* __restrict__ x, const float* __restrict__ xt,
    __hip_bfloat16* __restrict__ xb, __hip_bfloat16* __restrict__ xtb,
    float* __restrict__ xx, float* __restrict__ yy) {
  const int wid = threadIdx.x >> 6;
  const int lane = threadIdx.x & 63;
  int row = blockIdx.x * 4 + wid;
  const float* src;
  __hip_bfloat16* dst;
  float* nrm;
  if (row < M_DIM) {
    src = x + (size_t)row * D_DIM;
    dst = xb + (size_t)row * D_DIM;
    nrm = xx + row;
  } else {
    int r = row - M_DIM;
    src = xt + (size_t)r * D_DIM;
    dst = xtb + (size_t)r * D_DIM;
    nrm = yy + r;
  }
  const float4* s4 = (const float4*)src;
  float4 a = s4[lane];        // elements 4*lane   .. 4*lane+3
  float4 b = s4[lane + 64];   // elements 256+4*lane ..
  float nv = a.x * a.x + a.y * a.y + a.z * a.z + a.w * a.w +
             b.x * b.x + b.y * b.y + b.z * b.z + b.w * b.w;
  union { __hip_bfloat16 h[4]; int2 v; } ua, ub;
  ua.h[0] = __float2bfloat16(a.x); ua.h[1] = __float2bfloat16(a.y);
  ua.h[2] = __float2bfloat16(a.z); ua.h[3] = __float2bfloat16(a.w);
  ub.h[0] = __float2bfloat16(b.x); ub.h[1] = __float2bfloat16(b.y);
  ub.h[2] = __float2bfloat16(b.z); ub.h[3] = __float2bfloat16(b.w);
  ((int2*)dst)[lane] = ua.v;
  ((int2*)dst)[lane + 64] = ub.v;
#pragma unroll
  for (int off = 32; off; off >>= 1) nv += __shfl_xor(nv, off, 64);
  if (lane == 0) *nrm = nv;
}

__global__ void init_out(float* __restrict__ out, const float* __restrict__ bias) {
  int i = blockIdx.x * blockDim.x + threadIdx.x;
  if (i < M_DIM) out[i] = bias[0];
}

// 128x128 tile, BK=64, 4 waves (2x2), each wave 4x4 MFMA 16x16x32 tiles.
// LDS chunk positions XOR-swizzled: row r stores k-chunk c at position c^(r&7),
// so ds_read_b128 fragment reads spread across 8 bank groups (2-way = free).
__global__ __launch_bounds__(256) void rbf_gemm(
    const __hip_bfloat16* __restrict__ A,  // [M][D] bf16
    const __hip_bfloat16* __restrict__ B,  // [N][D] bf16
    const float* __restrict__ xx, const float* __restrict__ yy,
    const float* __restrict__ w, const float* __restrict__ gamma,
    float* __restrict__ out) {
  __shared__ __hip_bfloat16 As[BM * BK];  // 16 KB, [128 rows][8 chunks of 16B]
  __shared__ __hip_bfloat16 Bs[BN * BK];  // 16 KB
  __shared__ float rowsum[BM];

  const int tid = threadIdx.x;
  const int lane = tid & 63;
  const int wid = tid >> 6;
  const int wm = wid >> 1;  // 0..1
  const int wn = wid & 1;   // 0..1
  const int bm = blockIdx.y, bn = blockIdx.x;

  if (tid < BM) rowsum[tid] = 0.0f;

  const size_t a_base = (size_t)bm * BM * D_DIM;
  const size_t b_base = (size_t)bn * BN * D_DIM;

  f32x4 acc[4][4];
  const f32x4 zero = {0.f, 0.f, 0.f, 0.f};
#pragma unroll
  for (int i = 0; i < 4; i++)
#pragma unroll
    for (int j = 0; j < 4; j++) acc[i][j] = zero;

  const int frow = lane & 15;  // fragment row/col within 16x16
  const int fk8 = lane >> 4;   // which 8-element k-chunk within 32 (0..3)

  for (int kt = 0; kt < KITERS; ++kt) {
    __syncthreads();  // previous tile fully consumed (also covers rowsum init)
    const int k0 = kt * BK;
    // Stage A,B tiles: 128 rows x 8 chunks = 1024 slots, 4 issues x 256 threads.
    // Slot (row,pos) receives global chunk pos^(row&7).
#pragma unroll
    for (int issue = 0; issue < 4; ++issue) {
      int slot = issue * 256 + tid;
      int row = slot >> 3, pos = slot & 7;
      int chunk = pos ^ (row & 7);
      char* ldst = (char*)nullptr;  // (dest computed as wave-uniform base below)
      (void)ldst;
      gload_lds16(A + a_base + (size_t)row * D_DIM + k0 + chunk * 8,
                  (char*)As + (size_t)(issue * 256 + wid * 64) * 16);
      gload_lds16(B + b_base + (size_t)row * D_DIM + k0 + chunk * 8,
                  (char*)Bs + (size_t)(issue * 256 + wid * 64) * 16);
    }
    __syncthreads();  // staged (compiler drains vmcnt before barrier)

#pragma unroll
    for (int ksub = 0; ksub < 2; ++ksub) {
      bf16x8 af[4], bfr[4];
#pragma unroll
      for (int i = 0; i < 4; i++) {
        int row = wm * 64 + i * 16 + frow;
        int p = (ksub * 4 + fk8) ^ (frow & 7);
        af[i] = *(const bf16x8*)((const char*)As + row * (BK * 2) + p * 16);
      }
#pragma unroll
      for (int j = 0; j < 4; j++) {
        int col = wn * 64 + j * 16 + frow;
        int p = (ksub * 4 + fk8) ^ (frow & 7);
        bfr[j] = *(const bf16x8*)((const char*)Bs + col * (BK * 2) + p * 16);
      }
#pragma unroll
      for (int i = 0; i < 4; i++)
#pragma unroll
        for (int j = 0; j < 4; j++)
          acc[i][j] = __builtin_amdgcn_mfma_f32_16x16x32_bf16(af[i], bfr[j],
                                                              acc[i][j], 0, 0, 0);
    }
  }

  // Epilogue. C layout: col = lane&15, row = (lane>>4)*4 + reg.
  const float g = gamma[0];
  float yv[4], wv[4];
#pragma unroll
  for (int j = 0; j < 4; j++) {
    int n = bn * BN + wn * 64 + j * 16 + frow;
    yv[j] = yy[n];
    wv[j] = w[n];
  }
#pragma unroll
  for (int i = 0; i < 4; i++) {
#pragma unroll
    for (int r = 0; r < 4; r++) {
      int mrow = wm * 64 + i * 16 + fk8 * 4 + r;  // local row in [0,128)
      float xv = xx[bm * BM + mrow];
      float s = 0.f;
#pragma unroll
      for (int j = 0; j < 4; j++) {
        float v = acc[i][j][r];
        float sq = fmaxf(xv + yv[j] - 2.0f * v, 0.0f);
        s += wv[j] * __expf(-g * sq);
      }
      // reduce the 16 cols held across the 16-lane group
      s += __shfl_xor(s, 1, 64);
      s += __shfl_xor(s, 2, 64);
      s += __shfl_xor(s, 4, 64);
      s += __shfl_xor(s, 8, 64);
      if (frow == 0) atomicAdd(&rowsum[mrow], s);
    }
  }
  __syncthreads();
  if (tid < BM) atomicAdd(&out[bm * BM + tid], rowsum[tid]);
}

extern "C" void kernel_launch(void* const* d_in, const int* in_sizes, int n_in,
                              void* d_out, int out_size, void* d_ws, size_t ws_size,
                              hipStream_t stream) {
  const float* x = (const float*)d_in[0];       // [8192,512]
  const float* xt = (const float*)d_in[1];      // [8192,512]
  const float* gamma = (const float*)d_in[2];   // [1]
  const float* weight = (const float*)d_in[3];  // [8192,1]
  const float* bias = (const float*)d_in[4];    // [1]
  float* out = (float*)d_out;                   // [8192]

  char* ws = (char*)d_ws;
  __hip_bfloat16* xb = (__hip_bfloat16*)ws;                                   // 8 MB
  __hip_bfloat16* xtb = (__hip_bfloat16*)(ws + (size_t)8 * 1024 * 1024);      // 8 MB
  float* xx = (float*)(ws + (size_t)16 * 1024 * 1024);                        // 32 KB
  float* yy = (float*)(ws + (size_t)16 * 1024 * 1024 + 32 * 1024);            // 32 KB

  prep_kernel<<<(M_DIM + N_DIM) / 4, 256, 0, stream>>>(x, xt, xb, xtb, xx, yy);
  init_out<<<(M_DIM + 255) / 256, 256, 0, stream>>>(out, bias);
  dim3 grid(N_DIM / BN, M_DIM / BM);
  rbf_gemm<<<grid, 256, 0, stream>>>(xb, xtb, xx, yy, weight, gamma, out);
}

// Round 3
// 169.179 us; speedup vs baseline: 1.1751x; 1.1751x over previous
//
#include <hip/hip_runtime.h>
#include <hip/hip_bf16.h>
#include <stdint.h>

#define M_DIM 8192
#define N_DIM 8192
#define D_DIM 512
#define BM 128
#define BN 128
#define BK 32
#define KITERS (D_DIM / BK)   // 16

typedef __bf16 bf16x8 __attribute__((ext_vector_type(8)));
typedef float f32x4 __attribute__((ext_vector_type(4)));

__device__ inline void gload_lds16(const void* g, void* l) {
  __builtin_amdgcn_global_load_lds(
      (const __attribute__((address_space(1))) void*)g,
      (__attribute__((address_space(3))) void*)l, 16, 0, 0);
}

// 256 threads = 4 waves; one wave per row; coalesced. Blocks 0..31 also
// initialize out[] = bias (replaces the init_out kernel).
__global__ __launch_bounds__(256) void prep_kernel(
    const float* __restrict__ x, const float* __restrict__ xt,
    __hip_bfloat16* __restrict__ xb, __hip_bfloat16* __restrict__ xtb,
    float* __restrict__ xx, float* __restrict__ yy,
    float* __restrict__ out, const float* __restrict__ bias) {
  if (blockIdx.x < 32) out[blockIdx.x * 256 + threadIdx.x] = bias[0];
  const int wid = threadIdx.x >> 6;
  const int lane = threadIdx.x & 63;
  int row = blockIdx.x * 4 + wid;
  const float* src;
  __hip_bfloat16* dst;
  float* nrm;
  if (row < M_DIM) {
    src = x + (size_t)row * D_DIM;
    dst = xb + (size_t)row * D_DIM;
    nrm = xx + row;
  } else {
    int r = row - M_DIM;
    src = xt + (size_t)r * D_DIM;
    dst = xtb + (size_t)r * D_DIM;
    nrm = yy + r;
  }
  const float4* s4 = (const float4*)src;
  float4 a = s4[lane];
  float4 b = s4[lane + 64];
  float nv = a.x * a.x + a.y * a.y + a.z * a.z + a.w * a.w +
             b.x * b.x + b.y * b.y + b.z * b.z + b.w * b.w;
  union { __hip_bfloat16 h[4]; int2 v; } ua, ub;
  ua.h[0] = __float2bfloat16(a.x); ua.h[1] = __float2bfloat16(a.y);
  ua.h[2] = __float2bfloat16(a.z); ua.h[3] = __float2bfloat16(a.w);
  ub.h[0] = __float2bfloat16(b.x); ub.h[1] = __float2bfloat16(b.y);
  ub.h[2] = __float2bfloat16(b.z); ub.h[3] = __float2bfloat16(b.w);
  ((int2*)dst)[lane] = ua.v;
  ((int2*)dst)[lane + 64] = ub.v;
#pragma unroll
  for (int off = 32; off; off >>= 1) nv += __shfl_xor(nv, off, 64);
  if (lane == 0) *nrm = nv;
}

// 128x128 tile, BK=32, 4 waves (2x2). Operand-swapped MFMA: A-op = y-frags,
// B-op = x-frags, so C lane dim = m and register dim = n -> N-reduction is
// in-register; only an fk8 (4-way) shuffle reduce remains.
// LDS swizzle: row r stores 16B chunk c at pos c^((r>>1)&3): fragment reads
// spread 16 lanes over 8 bank groups (2-way = free); staging stays coalesced.
// Block swizzle: 8x8 (bm,bn) clusters per XCD -> A+B tiles resident in L2.
__global__ __launch_bounds__(256) void rbf_gemm(
    const __hip_bfloat16* __restrict__ A,  // [M][D] bf16
    const __hip_bfloat16* __restrict__ B,  // [N][D] bf16
    const float* __restrict__ xx, const float* __restrict__ yy,
    const float* __restrict__ w, const float* __restrict__ gamma,
    float* __restrict__ out) {
  __shared__ __hip_bfloat16 As[BM * BK];  // 8 KB, [128 rows][4 chunks of 16B]
  __shared__ __hip_bfloat16 Bs[BN * BK];  // 8 KB
  __shared__ float rowsum[BM];

  const int tid = threadIdx.x;
  const int lane = tid & 63;
  const int wid = tid >> 6;
  const int wm = wid >> 1;  // 0..1  (M half)
  const int wn = wid & 1;   // 0..1  (N half)

  // XCD-aware swizzle: b = g*512 + p*8 + x -> cluster (g,x) covers an 8x8 tile
  // region; with round-robin XCD = b%8, each XCD works a 2 MB-resident region.
  const int b = blockIdx.x;
  const int g = b >> 9;
  const int xcd = b & 7;
  const int p = (b >> 3) & 63;
  const int bm = g * 8 + (p >> 3);
  const int bn = xcd * 8 + (p & 7);

  if (tid < BM) rowsum[tid] = 0.0f;

  const size_t a_base = (size_t)bm * BM * D_DIM;
  const size_t b_base = (size_t)bn * BN * D_DIM;

  f32x4 acc[4][4];  // [i = n-tile][j = m-tile]
  const f32x4 zero = {0.f, 0.f, 0.f, 0.f};
#pragma unroll
  for (int i = 0; i < 4; i++)
#pragma unroll
    for (int j = 0; j < 4; j++) acc[i][j] = zero;

  const int frow = lane & 15;  // non-K index within 16
  const int fk8 = lane >> 4;   // 8-element k-chunk (0..3)

  for (int kt = 0; kt < KITERS; ++kt) {
    __syncthreads();  // previous tile consumed (also covers rowsum init)
    const int k0 = kt * BK;
    // Stage: 128 rows x 4 chunks = 512 slots per tile, 2 issues x 256 threads.
    // Slot (row,pos) <- global chunk pos^((row>>1)&3).
#pragma unroll
    for (int issue = 0; issue < 2; ++issue) {
      int slot = issue * 256 + tid;
      int row = slot >> 2, pos = slot & 3;
      int chunk = pos ^ ((row >> 1) & 3);
      gload_lds16(A + a_base + (size_t)row * D_DIM + k0 + chunk * 8,
                  (char*)As + (size_t)(issue * 256 + wid * 64) * 16);
      gload_lds16(B + b_base + (size_t)row * D_DIM + k0 + chunk * 8,
                  (char*)Bs + (size_t)(issue * 256 + wid * 64) * 16);
    }
    __syncthreads();  // staged

    bf16x8 an[4], am[4];
#pragma unroll
    for (int i = 0; i < 4; i++) {  // y fragments (N rows)
      int row = wn * 64 + i * 16 + frow;
      int pos = fk8 ^ ((row >> 1) & 3);
      an[i] = *(const bf16x8*)((const char*)Bs + row * (BK * 2) + pos * 16);
    }
#pragma unroll
    for (int j = 0; j < 4; j++) {  // x fragments (M rows)
      int row = wm * 64 + j * 16 + frow;
      int pos = fk8 ^ ((row >> 1) & 3);
      am[j] = *(const bf16x8*)((const char*)As + row * (BK * 2) + pos * 16);
    }
#pragma unroll
    for (int i = 0; i < 4; i++)
#pragma unroll
      for (int j = 0; j < 4; j++)
        acc[i][j] = __builtin_amdgcn_mfma_f32_16x16x32_bf16(an[i], am[j],
                                                            acc[i][j], 0, 0, 0);
  }

  // Epilogue. C layout (swapped operands): m = lane&15, n = (lane>>4)*4 + reg.
  const float g2 = gamma[0];
  float xv[4];
#pragma unroll
  for (int j = 0; j < 4; j++)
    xv[j] = xx[bm * BM + wm * 64 + j * 16 + frow];
  float s[4] = {0.f, 0.f, 0.f, 0.f};
#pragma unroll
  for (int i = 0; i < 4; i++) {
#pragma unroll
    for (int r = 0; r < 4; r++) {
      int n = bn * BN + wn * 64 + i * 16 + fk8 * 4 + r;
      float yv = yy[n], wv = w[n];
#pragma unroll
      for (int j = 0; j < 4; j++) {
        float v = acc[i][j][r];
        float sq = fmaxf(xv[j] + yv - 2.0f * v, 0.0f);
        s[j] += wv * __expf(-g2 * sq);
      }
    }
  }
#pragma unroll
  for (int j = 0; j < 4; j++) {  // reduce over fk8 groups (lanes 16,32 apart)
    s[j] += __shfl_xor(s[j], 16, 64);
    s[j] += __shfl_xor(s[j], 32, 64);
  }
  if (lane < 16) {
#pragma unroll
    for (int j = 0; j < 4; j++)
      atomicAdd(&rowsum[wm * 64 + j * 16 + lane], s[j]);
  }
  __syncthreads();
  if (tid < BM) atomicAdd(&out[bm * BM + tid], rowsum[tid]);
}

extern "C" void kernel_launch(void* const* d_in, const int* in_sizes, int n_in,
                              void* d_out, int out_size, void* d_ws, size_t ws_size,
                              hipStream_t stream) {
  const float* x = (const float*)d_in[0];       // [8192,512]
  const float* xt = (const float*)d_in[1];      // [8192,512]
  const float* gamma = (const float*)d_in[2];   // [1]
  const float* weight = (const float*)d_in[3];  // [8192,1]
  const float* bias = (const float*)d_in[4];    // [1]
  float* out = (float*)d_out;                   // [8192]

  char* ws = (char*)d_ws;
  __hip_bfloat16* xb = (__hip_bfloat16*)ws;                                   // 8 MB
  __hip_bfloat16* xtb = (__hip_bfloat16*)(ws + (size_t)8 * 1024 * 1024);      // 8 MB
  float* xx = (float*)(ws + (size_t)16 * 1024 * 1024);                        // 32 KB
  float* yy = (float*)(ws + (size_t)16 * 1024 * 1024 + 32 * 1024);            // 32 KB

  prep_kernel<<<(M_DIM + N_DIM) / 4, 256, 0, stream>>>(x, xt, xb, xtb, xx, yy,
                                                       out, bias);
  rbf_gemm<<<(M_DIM / BM) * (N_DIM / BN), 256, 0, stream>>>(xb, xtb, xx, yy,
                                                            weight, gamma, out);
}

// Round 4
// 140.714 us; speedup vs baseline: 1.4128x; 1.2023x over previous
//
#include <hip/hip_runtime.h>
#include <hip/hip_bf16.h>
#include <stdint.h>

#define M_DIM 8192
#define N_DIM 8192
#define D_DIM 512          // elements; 512 bytes per row in fp8
#define BM 128
#define BN 128
#define BKB 128            // K-bytes (=elements) per tile step, fp8
#define KITERS (D_DIM / BKB)   // 4

typedef int v8i __attribute__((ext_vector_type(8)));
typedef float f32x4 __attribute__((ext_vector_type(4)));

__device__ inline void gload_lds16(const void* g, void* l) {
  __builtin_amdgcn_global_load_lds(
      (const __attribute__((address_space(1))) void*)g,
      (__attribute__((address_space(3))) void*)l, 16, 0, 0);
}

// 256 threads = 4 waves; one wave per row: fp32 -> fp8(e4m3) + squared norm.
// Blocks 0..31 also initialize out[] = bias.
__global__ __launch_bounds__(256) void prep_kernel(
    const float* __restrict__ x, const float* __restrict__ xt,
    char* __restrict__ xb, char* __restrict__ xtb,
    float* __restrict__ xx, float* __restrict__ yy,
    float* __restrict__ out, const float* __restrict__ bias) {
  if (blockIdx.x < 32) out[blockIdx.x * 256 + threadIdx.x] = bias[0];
  const int wid = threadIdx.x >> 6;
  const int lane = threadIdx.x & 63;
  int row = blockIdx.x * 4 + wid;
  const float* src;
  char* dst;
  float* nrm;
  if (row < M_DIM) {
    src = x + (size_t)row * D_DIM;
    dst = xb + (size_t)row * D_DIM;
    nrm = xx + row;
  } else {
    int r = row - M_DIM;
    src = xt + (size_t)r * D_DIM;
    dst = xtb + (size_t)r * D_DIM;
    nrm = yy + r;
  }
  const float4* s4 = (const float4*)src;
  float4 a = s4[lane * 2];      // elements 8*lane   .. 8*lane+3
  float4 b = s4[lane * 2 + 1];  // elements 8*lane+4 .. 8*lane+7
  float nv = a.x * a.x + a.y * a.y + a.z * a.z + a.w * a.w +
             b.x * b.x + b.y * b.y + b.z * b.z + b.w * b.w;
  // Pack 8 floats -> 8 e4m3 bytes. (Pair ordering inside the pack is the same
  // K-permutation for A and B, so dot products are unaffected regardless.)
  int w0 = __builtin_amdgcn_cvt_pk_fp8_f32(a.x, a.y, 0, false);
  w0 = __builtin_amdgcn_cvt_pk_fp8_f32(a.z, a.w, w0, true);
  int w1 = __builtin_amdgcn_cvt_pk_fp8_f32(b.x, b.y, 0, false);
  w1 = __builtin_amdgcn_cvt_pk_fp8_f32(b.z, b.w, w1, true);
  int2 pk; pk.x = w0; pk.y = w1;
  ((int2*)dst)[lane] = pk;
#pragma unroll
  for (int off = 32; off; off >>= 1) nv += __shfl_xor(nv, off, 64);
  if (lane == 0) *nrm = nv;
}

// 128x128 tile, MX-fp8 K=128 MFMA, 4 waves (2x2), 4 K-iterations.
// Operand-swapped: A-op = y-frags (n), B-op = x-frags (m) -> C: m=lane&15,
// n=(lane>>4)*4+reg; N-reduction mostly in-register.
// LDS: row r (128 B) stores 16B chunk c at pos c^(r&7) -> fragment reads are
// 2-way bank aliasing (free); staging stays lane-contiguous for global_load_lds.
__global__ __launch_bounds__(256) void rbf_gemm(
    const char* __restrict__ A,  // [M][512] fp8 bytes
    const char* __restrict__ B,  // [N][512] fp8 bytes
    const float* __restrict__ xx, const float* __restrict__ yy,
    const float* __restrict__ w, const float* __restrict__ gamma,
    float* __restrict__ out) {
  __shared__ __align__(16) char As[BM * BKB];  // 16 KB
  __shared__ __align__(16) char Bs[BN * BKB];  // 16 KB
  __shared__ float rowsum[BM];

  const int tid = threadIdx.x;
  const int lane = tid & 63;
  const int wid = tid >> 6;
  const int wm = wid >> 1;  // M half
  const int wn = wid & 1;   // N half

  // XCD-aware swizzle: 8x8 tile clusters per XCD (L2-resident A+B region).
  const int b = blockIdx.x;
  const int g = b >> 9;
  const int xcd = b & 7;
  const int p = (b >> 3) & 63;
  const int bm = g * 8 + (p >> 3);
  const int bn = xcd * 8 + (p & 7);

  if (tid < BM) rowsum[tid] = 0.0f;

  const size_t a_base = (size_t)bm * BM * D_DIM;
  const size_t b_base = (size_t)bn * BN * D_DIM;

  f32x4 acc[4][4];  // [i = n-tile][j = m-tile]
  const f32x4 zero = {0.f, 0.f, 0.f, 0.f};
#pragma unroll
  for (int i = 0; i < 4; i++)
#pragma unroll
    for (int j = 0; j < 4; j++) acc[i][j] = zero;

  const int frow = lane & 15;  // non-K index within 16
  const int fk8 = lane >> 4;   // which 32-byte K-chunk (0..3)
  const int p0 = (2 * fk8) ^ (frow & 7);  // swizzled pos of 16B chunk 2*fk8
  const int p1 = p0 ^ 1;                  // chunk 2*fk8+1
  const int sc1 = 127;  // e8m0 scale byte 127 -> x1.0

  for (int kt = 0; kt < KITERS; ++kt) {
    __syncthreads();  // previous tile consumed (also covers rowsum init)
    const int k0 = kt * BKB;
    // Stage: 128 rows x 8 chunks = 1024 slots per matrix, 4 issues x 256 thr.
    // Slot (row,pos) <- global chunk pos^(row&7).
#pragma unroll
    for (int issue = 0; issue < 4; ++issue) {
      int slot = issue * 256 + tid;
      int row = slot >> 3, pos = slot & 7;
      int chunk = pos ^ (row & 7);
      gload_lds16(A + a_base + (size_t)row * D_DIM + k0 + chunk * 16,
                  As + (size_t)(issue * 256 + wid * 64) * 16);
      gload_lds16(B + b_base + (size_t)row * D_DIM + k0 + chunk * 16,
                  Bs + (size_t)(issue * 256 + wid * 64) * 16);
    }
    __syncthreads();  // staged

    v8i an[4], am[4];
#pragma unroll
    for (int i = 0; i < 4; i++) {  // y fragments (N rows)
      int row = wn * 64 + i * 16 + frow;
      union { int4 q[2]; v8i v; } u;
      u.q[0] = *(const int4*)(Bs + row * BKB + p0 * 16);
      u.q[1] = *(const int4*)(Bs + row * BKB + p1 * 16);
      an[i] = u.v;
    }
#pragma unroll
    for (int j = 0; j < 4; j++) {  // x fragments (M rows)
      int row = wm * 64 + j * 16 + frow;
      union { int4 q[2]; v8i v; } u;
      u.q[0] = *(const int4*)(As + row * BKB + p0 * 16);
      u.q[1] = *(const int4*)(As + row * BKB + p1 * 16);
      am[j] = u.v;
    }
#pragma unroll
    for (int i = 0; i < 4; i++)
#pragma unroll
      for (int j = 0; j < 4; j++)
        acc[i][j] = __builtin_amdgcn_mfma_scale_f32_16x16x128_f8f6f4(
            an[i], am[j], acc[i][j], 0, 0, /*opsel_a*/ 0, sc1, /*opsel_b*/ 0,
            sc1);
  }

  // Epilogue. C layout (swapped operands): m = lane&15, n = (lane>>4)*4 + reg.
  const float g2 = gamma[0];
  float xv[4];
#pragma unroll
  for (int j = 0; j < 4; j++)
    xv[j] = xx[bm * BM + wm * 64 + j * 16 + frow];
  float s[4] = {0.f, 0.f, 0.f, 0.f};
#pragma unroll
  for (int i = 0; i < 4; i++) {
#pragma unroll
    for (int r = 0; r < 4; r++) {
      int n = bn * BN + wn * 64 + i * 16 + fk8 * 4 + r;
      float yv = yy[n], wv = w[n];
#pragma unroll
      for (int j = 0; j < 4; j++) {
        float v = acc[i][j][r];
        float sq = fmaxf(xv[j] + yv - 2.0f * v, 0.0f);
        s[j] += wv * __expf(-g2 * sq);
      }
    }
  }
#pragma unroll
  for (int j = 0; j < 4; j++) {  // reduce over fk8 groups (lanes 16,32 apart)
    s[j] += __shfl_xor(s[j], 16, 64);
    s[j] += __shfl_xor(s[j], 32, 64);
  }
  if (lane < 16) {
#pragma unroll
    for (int j = 0; j < 4; j++)
      atomicAdd(&rowsum[wm * 64 + j * 16 + lane], s[j]);
  }
  __syncthreads();
  if (tid < BM) atomicAdd(&out[bm * BM + tid], rowsum[tid]);
}

extern "C" void kernel_launch(void* const* d_in, const int* in_sizes, int n_in,
                              void* d_out, int out_size, void* d_ws, size_t ws_size,
                              hipStream_t stream) {
  const float* x = (const float*)d_in[0];       // [8192,512]
  const float* xt = (const float*)d_in[1];      // [8192,512]
  const float* gamma = (const float*)d_in[2];   // [1]
  const float* weight = (const float*)d_in[3];  // [8192,1]
  const float* bias = (const float*)d_in[4];    // [1]
  float* out = (float*)d_out;                   // [8192]

  char* ws = (char*)d_ws;
  char* xb = ws;                                             // 4 MB fp8
  char* xtb = ws + (size_t)4 * 1024 * 1024;                  // 4 MB fp8
  float* xx = (float*)(ws + (size_t)8 * 1024 * 1024);        // 32 KB
  float* yy = (float*)(ws + (size_t)8 * 1024 * 1024 + 32 * 1024);  // 32 KB

  prep_kernel<<<(M_DIM + N_DIM) / 4, 256, 0, stream>>>(x, xt, xb, xtb, xx, yy,
                                                       out, bias);
  rbf_gemm<<<(M_DIM / BM) * (N_DIM / BN), 256, 0, stream>>>(xb, xtb, xx, yy,
                                                            weight, gamma, out);
}